// Round 5
// baseline (586.975 us; speedup 1.0000x reference)
//
#include <hip/hip_runtime.h>
#include <math.h>

// ---------------------------------------------------------------------------
// VQ-VAE-ish CIFAR pipeline, fp32 throughout (argmin flip-sensitivity forbids
// bf16 anywhere before the VQ stage).
//
// R4 -> R5: occupancy-vs-VGPR fix. R4's k3 compiled to VGPR=56 (compiler
// targeted 8 waves/SIMD the 512-block grid can never reach), so pt[4][16]
// never lived in registers -> LDS re-reads serialized VALU and LDS pipes.
// __launch_bounds__(384,3) / (256,4) unlock ~168/128 VGPRs to match the
// grid-limited occupancy. k5's weight reads were 16-way bank-conflicted
// (stride 144 = 16 mod 32) -> transposed to bank-striped [r][c] layout.
// ---------------------------------------------------------------------------

#define CNT1 460800.0   /* 2048*15*15 */
#define CNT2 73728.0    /* 2048*6*6   */
#define CNT3 32768.0    /* 2048*4*4   */

// ---------------- K0: pack w2 -> [cc8][r=ci*9+s][cog][half] ----------------
// half 0 -> co=cog, half 1 -> co=cog+16, so a float2 read gives both.
__global__ void k0_w2t(const float* __restrict__ w2, float* __restrict__ w2t)
{
  const int idx = blockIdx.x * 256 + threadIdx.x;   // 18432 total
  const int half = idx & 1, cog = (idx >> 1) & 15;
  const int r = (idx >> 5) % 72, cc = idx / 2304;
  const int o = cog + 16 * half;
  w2t[idx] = w2[o * 576 + cc * 72 + r];
}

// ---------------- k1 segment helper ----------------
// CB: base input col (mult of 4), W4: float4s per row, J0/CNT: pooled cols.
template<int CB, int W4, int J0, int CNT>
__device__ __forceinline__ void conv1_seg(const float* img, const float* wr,
                                          int prow, float bias, float* vout)
{
  float acc[CNT][4];
#pragma unroll
  for (int j = 0; j < CNT; ++j) { acc[j][0] = 0; acc[j][1] = 0; acc[j][2] = 0; acc[j][3] = 0; }
#pragma unroll
  for (int cin = 0; cin < 3; ++cin) {
    float pt[4][4 * W4];
    const float4* src = (const float4*)&img[cin * 1024 + (2 * prow) * 32 + CB];
#pragma unroll
    for (int r = 0; r < 4; ++r)
#pragma unroll
      for (int u = 0; u < W4; ++u) {
        float4 f = src[r * 8 + u];
        pt[r][u * 4 + 0] = f.x; pt[r][u * 4 + 1] = f.y;
        pt[r][u * 4 + 2] = f.z; pt[r][u * 4 + 3] = f.w;
      }
#pragma unroll
    for (int jj = 0; jj < CNT; ++jj) {
      const int c0 = 2 * (J0 + jj) - CB;
#pragma unroll
      for (int kh = 0; kh < 3; ++kh)
#pragma unroll
        for (int kw = 0; kw < 3; ++kw) {
          const float w_ = wr[cin * 9 + kh * 3 + kw];
          acc[jj][0] += pt[kh][c0 + kw] * w_;
          acc[jj][1] += pt[kh][c0 + 1 + kw] * w_;
          acc[jj][2] += pt[kh + 1][c0 + kw] * w_;
          acc[jj][3] += pt[kh + 1][c0 + 1 + kw] * w_;
        }
    }
  }
#pragma unroll
  for (int jj = 0; jj < CNT; ++jj) {
    float v = fmaxf(fmaxf(acc[jj][0], acc[jj][1]), fmaxf(acc[jj][2], acc[jj][3])) + bias;
    vout[J0 + jj] = fmaxf(v, 0.f);
  }
}

// ---------------- K1 fast: conv1+pool+relu -> y1 + stats ----------------
// thread = (ch 0..63, rslot 0..3); each wave = one rslot -> all LDS reads
// are full-wave broadcasts. Row task = full 15 pooled cols via 3 b128-aligned
// segments. (256,4): 128 VGPR so pt/acc live in registers.
__global__ __launch_bounds__(256, 4) void k1_conv1(
    const float* __restrict__ x, const float* __restrict__ w1,
    const float* __restrict__ b1, double* __restrict__ dstats,
    float* __restrict__ y1)
{
  __shared__ float img[3072];
  __shared__ float red_s[256], red_q[256];
  const int n = blockIdx.x, t = threadIdx.x;
  const float4* xin = (const float4*)(x + n * 3072);
  float4* img4 = (float4*)img;
  for (int i = t; i < 768; i += 256) img4[i] = xin[i];
  const int ch = t & 63, rslot = t >> 6;
  float wr[27];
#pragma unroll
  for (int k = 0; k < 27; ++k) wr[k] = w1[ch * 27 + k];
  const float bias = b1[ch];
  __syncthreads();
  float s = 0.f, ss = 0.f;
  for (int prow = rslot; prow < 15; prow += 4) {
    float vout[15];
    conv1_seg<0, 4, 0, 7>(img, wr, prow, bias, vout);
    conv1_seg<12, 4, 7, 5>(img, wr, prow, bias, vout);
    conv1_seg<24, 2, 12, 3>(img, wr, prow, bias, vout);
    float4* dst = (float4*)(y1 + n * 15360 + ch * 240 + prow * 16);
    dst[0] = make_float4(vout[0], vout[1], vout[2], vout[3]);
    dst[1] = make_float4(vout[4], vout[5], vout[6], vout[7]);
    dst[2] = make_float4(vout[8], vout[9], vout[10], vout[11]);
    dst[3] = make_float4(vout[12], vout[13], vout[14], 0.f);
#pragma unroll
    for (int j = 0; j < 15; ++j) { s += vout[j]; ss += vout[j] * vout[j]; }
  }
  red_s[t] = s; red_q[t] = ss;
  __syncthreads();
  if (t < 64) {
    float rs = red_s[t] + red_s[t + 64] + red_s[t + 128] + red_s[t + 192];
    float rq = red_q[t] + red_q[t + 64] + red_q[t + 128] + red_q[t + 192];
    atomicAdd(&dstats[t * 16], (double)rs);
    atomicAdd(&dstats[t * 16 + 8], (double)rq);
  }
}

// ---------------- K1 fallback (stats only) ----------------
__global__ __launch_bounds__(256) void k1_conv1_stats(
    const float* __restrict__ x, const float* __restrict__ w1,
    const float* __restrict__ b1, double* __restrict__ dstats)
{
  __shared__ float img[3072];
  __shared__ float red[512];
  const int n = blockIdx.x, t = threadIdx.x;
  const float4* xin = (const float4*)(x + n * 3072);
  float4* img4 = (float4*)img;
  for (int i = t; i < 768; i += 256) img4[i] = xin[i];
  const int c = t >> 2, q = t & 3;
  float wr[27];
#pragma unroll
  for (int k = 0; k < 27; ++k) wr[k] = w1[c * 27 + k];
  const float bias = b1[c];
  __syncthreads();
  float s = 0.f, ss = 0.f;
  for (int p = q; p < 225; p += 4) {
    const int i = p / 15, j = p % 15;
    float a0 = 0, a1 = 0, a2 = 0, a3 = 0;
#pragma unroll
    for (int cin = 0; cin < 3; ++cin) {
      float pt[4][4];
#pragma unroll
      for (int r = 0; r < 4; ++r) {
        const float2* row = (const float2*)&img[cin * 1024 + (2 * i + r) * 32 + 2 * j];
        float2 u = row[0], v = row[1];
        pt[r][0] = u.x; pt[r][1] = u.y; pt[r][2] = v.x; pt[r][3] = v.y;
      }
#pragma unroll
      for (int kh = 0; kh < 3; ++kh)
#pragma unroll
        for (int kw = 0; kw < 3; ++kw) {
          const float wv = wr[cin * 9 + kh * 3 + kw];
          a0 += pt[kh][kw] * wv;     a1 += pt[kh][kw + 1] * wv;
          a2 += pt[kh + 1][kw] * wv; a3 += pt[kh + 1][kw + 1] * wv;
        }
    }
    float v = fmaxf(fmaxf(a0, a1), fmaxf(a2, a3)) + bias;
    v = fmaxf(v, 0.f);
    s += v; ss += v * v;
  }
  red[t * 2] = s; red[t * 2 + 1] = ss;
  __syncthreads();
  if (q == 0) {
    float rs = red[t * 2] + red[(t + 1) * 2] + red[(t + 2) * 2] + red[(t + 3) * 2];
    float rq = red[t * 2 + 1] + red[(t + 1) * 2 + 1] + red[(t + 2) * 2 + 1] + red[(t + 3) * 2 + 1];
    atomicAdd(&dstats[c * 16], (double)rs);
    atomicAdd(&dstats[c * 16 + 8], (double)rq);
  }
}

// ---------------- KF: finalize BN -> affine ----------------
__global__ void k_finalize(const double* __restrict__ dstats,
                           const float* __restrict__ scale, const float* __restrict__ bias,
                           float* __restrict__ a, float* __restrict__ b, int C, double inv_cnt)
{
  int c = threadIdx.x;
  if (c < C) {
    double mean = dstats[c * 16] * inv_cnt;
    double var = dstats[c * 16 + 8] * inv_cnt - mean * mean;
    double ai = (double)scale[c] / sqrt(var + 1e-5);
    a[c] = (float)ai;
    b[c] = (float)((double)bias[c] - mean * ai);
  }
}

// ---------------- K3 fast: BN1(y1) -> conv2 + pool + relu + stats ----------
// 384 threads, 4 images/block, 8-channel chunks. thread = (irow, img, cog),
// owns co={cog,cog+16} x full pooled row. (384,3): grid gives 12 waves/CU,
// so allow ~168 VGPR -> pt[4][16]/wv/acc all in registers.
__global__ __launch_bounds__(384, 3) void k3_conv2_fast(
    const float* __restrict__ y1, const float* __restrict__ a1f,
    const float* __restrict__ b1f, const float* __restrict__ w2t,
    const float* __restrict__ b2, float* __restrict__ y2,
    double* __restrict__ dstats2)
{
  __shared__ float y1n[4 * 1928];     // 4 imgs x (8ch x 240 + 8 pad)
  __shared__ float w2c[72 * 32];      // [r=ci*9+s][cog][half]
  __shared__ float sum2L[32], ss2L[32];
  const int t = threadIdx.x;
  const int n0 = blockIdx.x * 4;
  if (t < 32) { sum2L[t] = 0.f; ss2L[t] = 0.f; }
  const int irow = t / 64;            // 0..5, one per wave
  const int img = (t >> 4) & 3;
  const int cog = t & 15;

  float acc[2][6][4];
#pragma unroll
  for (int h = 0; h < 2; ++h)
#pragma unroll
    for (int j = 0; j < 6; ++j) { acc[h][j][0] = 0; acc[h][j][1] = 0; acc[h][j][2] = 0; acc[h][j][3] = 0; }

  for (int cc = 0; cc < 8; ++cc) {
    __syncthreads();
    // stage y1 chunk with BN1 affine (4 x 480 float4, coalesced)
    for (int idx = t; idx < 1920; idx += 384) {
      const int im = idx / 480, wi = idx - im * 480;
      const int ch = cc * 8 + wi / 60;
      const float an = a1f[ch], bn = b1f[ch];
      float4 v = ((const float4*)(y1 + (n0 + im) * 15360 + cc * 1920))[wi];
      v.x = an * v.x + bn; v.y = an * v.y + bn;
      v.z = an * v.z + bn; v.w = an * v.w + bn;
      ((float4*)y1n)[im * 482 + wi] = v;
    }
    // stage w2 chunk (576 float4, contiguous)
    for (int idx = t; idx < 576; idx += 384)
      ((float4*)w2c)[idx] = ((const float4*)(w2t + cc * 2304))[idx];
    __syncthreads();
    for (int ci = 0; ci < 8; ++ci) {
      float wv0[9], wv1[9];
#pragma unroll
      for (int s = 0; s < 9; ++s) {
        float2 wp = *(const float2*)&w2c[(ci * 9 + s) * 32 + cog * 2];
        wv0[s] = wp.x; wv1[s] = wp.y;
      }
      float pt[4][16];
      const float4* src = (const float4*)&y1n[img * 1928 + ci * 240 + 2 * irow * 16];
#pragma unroll
      for (int r = 0; r < 4; ++r)
#pragma unroll
        for (int u = 0; u < 4; ++u) {
          float4 f = src[r * 4 + u];
          pt[r][u * 4 + 0] = f.x; pt[r][u * 4 + 1] = f.y;
          pt[r][u * 4 + 2] = f.z; pt[r][u * 4 + 3] = f.w;
        }
#pragma unroll
      for (int j = 0; j < 6; ++j)
#pragma unroll
        for (int kh = 0; kh < 3; ++kh)
#pragma unroll
          for (int kw = 0; kw < 3; ++kw) {
            const float p00 = pt[kh][2 * j + kw],     p01 = pt[kh][2 * j + 1 + kw];
            const float p10 = pt[kh + 1][2 * j + kw], p11 = pt[kh + 1][2 * j + 1 + kw];
            const float w0 = wv0[kh * 3 + kw], w1_ = wv1[kh * 3 + kw];
            acc[0][j][0] += p00 * w0;  acc[0][j][1] += p01 * w0;
            acc[0][j][2] += p10 * w0;  acc[0][j][3] += p11 * w0;
            acc[1][j][0] += p00 * w1_; acc[1][j][1] += p01 * w1_;
            acc[1][j][2] += p10 * w1_; acc[1][j][3] += p11 * w1_;
          }
    }
  }
  // epilogue: pool+bias+relu, store y2, stats
  const int n = n0 + img;
#pragma unroll
  for (int half = 0; half < 2; ++half) {
    const int co = cog + half * 16;
    const float bias = b2[co];
    float s = 0.f, sq = 0.f;
#pragma unroll
    for (int j = 0; j < 6; ++j) {
      float v = fmaxf(fmaxf(acc[half][j][0], acc[half][j][1]),
                      fmaxf(acc[half][j][2], acc[half][j][3])) + bias;
      v = fmaxf(v, 0.f);
      y2[n * 1152 + co * 36 + irow * 6 + j] = v;
      s += v; sq += v * v;
    }
    atomicAdd(&sum2L[co], s);
    atomicAdd(&ss2L[co], sq);
  }
  __syncthreads();
  if (t < 32) {
    atomicAdd(&dstats2[t * 16], (double)sum2L[t]);
    atomicAdd(&dstats2[t * 16 + 8], (double)ss2L[t]);
  }
}

// ---------------- K3 fallback (R2 version): recompute conv1 in-block -------
__global__ __launch_bounds__(256) void k3_conv2(
    const float* __restrict__ x, const float* __restrict__ w1,
    const float* __restrict__ b1, const float* __restrict__ a1f,
    const float* __restrict__ b1f, const float* __restrict__ w2,
    const float* __restrict__ b2, float* __restrict__ y2,
    double* __restrict__ dstats2)
{
  __shared__ float img[3072];
  __shared__ float y1n[16 * 240];
  __shared__ float w2c[144 * 32];
  __shared__ float sum2L[32], ss2L[32];
  const int n = blockIdx.x, t = threadIdx.x;
  if (t < 32) { sum2L[t] = 0.f; ss2L[t] = 0.f; }
  const float4* xin = (const float4*)(x + n * 3072);
  float4* img4 = (float4*)img;
  for (int i = t; i < 768; i += 256) img4[i] = xin[i];

  const int co = t & 31, irow = t >> 5;
  const bool activeC = (irow < 6);

  float acc[6][4];
#pragma unroll
  for (int j = 0; j < 6; ++j) { acc[j][0] = 0; acc[j][1] = 0; acc[j][2] = 0; acc[j][3] = 0; }

  const int cA = t >> 4, qA = t & 15;

  for (int cc = 0; cc < 4; ++cc) {
    __syncthreads();
    {
      const int ch = cc * 16 + cA;
      float wr[27];
#pragma unroll
      for (int k = 0; k < 27; ++k) wr[k] = w1[ch * 27 + k];
      const float bias = b1[ch];
      const float an = a1f[ch], bn = b1f[ch];
      for (int p = qA; p < 225; p += 16) {
        const int i = p / 15, j = p % 15;
        float a0 = 0, a1 = 0, a2 = 0, a3 = 0;
#pragma unroll
        for (int cin = 0; cin < 3; ++cin) {
          float pt[4][4];
#pragma unroll
          for (int r = 0; r < 4; ++r) {
            const float2* row = (const float2*)&img[cin * 1024 + (2 * i + r) * 32 + 2 * j];
            float2 u = row[0], v = row[1];
            pt[r][0] = u.x; pt[r][1] = u.y; pt[r][2] = v.x; pt[r][3] = v.y;
          }
#pragma unroll
          for (int kh = 0; kh < 3; ++kh)
#pragma unroll
            for (int kw = 0; kw < 3; ++kw) {
              const float wv = wr[cin * 9 + kh * 3 + kw];
              a0 += pt[kh][kw] * wv;     a1 += pt[kh][kw + 1] * wv;
              a2 += pt[kh + 1][kw] * wv; a3 += pt[kh + 1][kw + 1] * wv;
            }
        }
        float v = fmaxf(fmaxf(a0, a1), fmaxf(a2, a3)) + bias;
        v = fmaxf(v, 0.f);
        y1n[cA * 240 + i * 16 + j] = an * v + bn;
      }
    }
    for (int idx = t; idx < 4608; idx += 256) {
      const int o = idx & 31, r = idx >> 5;
      w2c[r * 32 + o] = w2[o * 576 + cc * 144 + r];
    }
    __syncthreads();
    if (activeC) {
      for (int ci = 0; ci < 16; ++ci) {
        float wv[9];
#pragma unroll
        for (int s = 0; s < 9; ++s) wv[s] = w2c[(ci * 9 + s) * 32 + co];
        float pt[4][16];
        const float4* src = (const float4*)&y1n[ci * 240 + (2 * irow) * 16];
#pragma unroll
        for (int r = 0; r < 4; ++r)
#pragma unroll
          for (int u = 0; u < 4; ++u) {
            float4 f = src[r * 4 + u];
            pt[r][u * 4] = f.x; pt[r][u * 4 + 1] = f.y;
            pt[r][u * 4 + 2] = f.z; pt[r][u * 4 + 3] = f.w;
          }
#pragma unroll
        for (int j = 0; j < 6; ++j) {
#pragma unroll
          for (int kh = 0; kh < 3; ++kh)
#pragma unroll
            for (int kw = 0; kw < 3; ++kw) {
              const float w_ = wv[kh * 3 + kw];
              acc[j][0] += pt[kh][2 * j + kw] * w_;
              acc[j][1] += pt[kh][2 * j + 1 + kw] * w_;
              acc[j][2] += pt[kh + 1][2 * j + kw] * w_;
              acc[j][3] += pt[kh + 1][2 * j + 1 + kw] * w_;
            }
        }
      }
    }
  }
  if (activeC) {
    const float bias = b2[co];
    float s = 0.f, sq = 0.f;
#pragma unroll
    for (int j = 0; j < 6; ++j) {
      float v = fmaxf(fmaxf(acc[j][0], acc[j][1]), fmaxf(acc[j][2], acc[j][3])) + bias;
      v = fmaxf(v, 0.f);
      y2[n * 1152 + co * 36 + irow * 6 + j] = v;
      s += v; sq += v * v;
    }
    atomicAdd(&sum2L[co], s);
    atomicAdd(&ss2L[co], sq);
  }
  __syncthreads();
  if (t < 32) {
    atomicAdd(&dstats2[t * 16], (double)sum2L[t]);
    atomicAdd(&dstats2[t * 16 + 8], (double)ss2L[t]);
  }
}

// ---------------- K5: BN2 -> conv3 + bias + relu + stats ----------------
// w3c transposed to [r=ci*9+s][c] so the 32 c-lanes stripe all 32 banks
// (was stride-144 = 16-way conflict). (256,4) -> 128 VGPR.
__global__ __launch_bounds__(256, 4) void k5_conv3(
    const float* __restrict__ y2, const float* __restrict__ a2f,
    const float* __restrict__ b2f, const float* __restrict__ w3,
    const float* __restrict__ b3, float* __restrict__ t3,
    double* __restrict__ dstats3)
{
  __shared__ float y2n[8 * 1152];
  __shared__ float w3c[144 * 32];   // [r][c]
  __shared__ float sum3L[32], ss3L[32];
  const int blk = blockIdx.x, t = threadIdx.x;
  if (t < 32) { sum3L[t] = 0.f; ss3L[t] = 0.f; }
  for (int idx = t; idx < 9216; idx += 256) {
    const int ci = (idx % 1152) / 36;
    y2n[idx] = a2f[ci] * y2[blk * 9216 + idx] + b2f[ci];
  }
  const int il = t >> 5, c = t & 31;
  float acc[16];
#pragma unroll
  for (int p = 0; p < 16; ++p) acc[p] = 0.f;
  for (int ch = 0; ch < 2; ++ch) {
    __syncthreads();
    for (int idx = t; idx < 4608; idx += 256) {
      const int o = idx & 31, r = idx >> 5;
      w3c[r * 32 + o] = w3[o * 288 + ch * 144 + r];
    }
    __syncthreads();
    for (int ci = 0; ci < 16; ++ci) {
      float wv[9];
#pragma unroll
      for (int s = 0; s < 9; ++s) wv[s] = w3c[(ci * 9 + s) * 32 + c];
      float pt[36];
      const float4* src = (const float4*)&y2n[il * 1152 + (ch * 16 + ci) * 36];
#pragma unroll
      for (int u = 0; u < 9; ++u) {
        float4 f = src[u];
        pt[u * 4] = f.x; pt[u * 4 + 1] = f.y; pt[u * 4 + 2] = f.z; pt[u * 4 + 3] = f.w;
      }
#pragma unroll
      for (int i = 0; i < 4; ++i)
#pragma unroll
        for (int j = 0; j < 4; ++j) {
          float a_ = 0.f;
#pragma unroll
          for (int kh = 0; kh < 3; ++kh)
#pragma unroll
            for (int kw = 0; kw < 3; ++kw)
              a_ += pt[(i + kh) * 6 + j + kw] * wv[kh * 3 + kw];
          acc[i * 4 + j] += a_;
        }
    }
  }
  const float bias = b3[c];
  float s = 0.f, sq = 0.f;
  float vout[16];
#pragma unroll
  for (int p = 0; p < 16; ++p) {
    float v = fmaxf(acc[p] + bias, 0.f);
    vout[p] = v; s += v; sq += v * v;
  }
  const int n = blk * 8 + il;
  float4* dst = (float4*)&t3[(n * 32 + c) * 16];
#pragma unroll
  for (int u = 0; u < 4; ++u)
    dst[u] = make_float4(vout[u * 4], vout[u * 4 + 1], vout[u * 4 + 2], vout[u * 4 + 3]);
  atomicAdd(&sum3L[c], s);
  atomicAdd(&ss3L[c], sq);
  __syncthreads();
  if (t < 32) {
    atomicAdd(&dstats3[t * 16], (double)sum3L[t]);
    atomicAdd(&dstats3[t * 16 + 8], (double)ss3L[t]);
  }
}

// ---------------- K8: BN3 affine + VQ ----------------
__global__ __launch_bounds__(256) void k8_vq(
    const float* __restrict__ t3, const float* __restrict__ a3f,
    const float* __restrict__ b3f, const float* __restrict__ cbg,
    float* __restrict__ recon, float* __restrict__ hout,
    double* __restrict__ dloss)
{
  __shared__ float cb[3200];
  __shared__ float n2[100];
  const int t = threadIdx.x;
  for (int i = t; i < 3200; i += 256) cb[i] = cbg[i];
  __syncthreads();
  if (t < 100) {
    float s = 0.f;
#pragma unroll
    for (int c = 0; c < 32; ++c) { float v = cb[t * 32 + c]; s += v * v; }
    n2[t] = s;
  }
  __syncthreads();
  const int v = blockIdx.x * 256 + t;
  const int b = v >> 4, p = v & 15;
  float z[32];
  float z2 = 0.f;
#pragma unroll
  for (int c = 0; c < 32; ++c) {
    const float zz = a3f[c] * t3[b * 512 + c * 16 + p] + b3f[c];
    hout[b * 512 + c * 16 + p] = zz;
    z[c] = zz; z2 += zz * zz;
  }
  float best = 1e30f; int bi = 0;
  for (int k = 0; k < 100; ++k) {
    float dot = 0.f;
#pragma unroll
    for (int c = 0; c < 32; ++c) dot += z[c] * cb[k * 32 + c];
    const float d = z2 + n2[k] - 2.f * dot;
    if (d < best) { best = d; bi = k; }
  }
  float lsum = 0.f;
#pragma unroll
  for (int c = 0; c < 32; ++c) {
    const float qv = cb[bi * 32 + c];
    recon[b * 512 + c * 16 + p] = qv;
    const float df = qv - z[c];
    lsum += df * df;
  }
#pragma unroll
  for (int off = 32; off > 0; off >>= 1) lsum += __shfl_down(lsum, off, 64);
  if ((t & 63) == 0) atomicAdd(dloss, (double)lsum);
}

// ---------------- K10: fc1+relu+fc2+log_softmax (+ vq_loss finalize) -------
__global__ __launch_bounds__(256) void k10_fc(
    const float* __restrict__ recon, const float* __restrict__ h,
    const float* __restrict__ fc1w, const float* __restrict__ fc1b,
    const float* __restrict__ fc2w, const float* __restrict__ fc2b,
    float* __restrict__ out, const double* __restrict__ dloss,
    float* __restrict__ loss_out)
{
  __shared__ float flat[4 * 512];
  __shared__ float z1[4 * 64];
  __shared__ float yL[4 * 10];
  const int t = threadIdx.x;
  const int w = t >> 6, l = t & 63;
  const int n = blockIdx.x * 4 + w;
  if (blockIdx.x == 0 && t == 0)
    loss_out[0] = (float)(1.25 * dloss[0] / (32768.0 * 32.0));
  for (int k = l; k < 512; k += 64)
    flat[w * 512 + k] = 0.5f * recon[n * 512 + k] + h[n * 512 + k];
  __syncthreads();
  float acc = fc1b[l];
  const float4* wrow = (const float4*)(fc1w + l * 512);
  const float4* frow = (const float4*)(flat + w * 512);
  for (int k4 = 0; k4 < 128; ++k4) {
    const float4 wv = wrow[k4], fv = frow[k4];
    acc += wv.x * fv.x + wv.y * fv.y + wv.z * fv.z + wv.w * fv.w;
  }
  z1[w * 64 + l] = fmaxf(acc, 0.f);
  __syncthreads();
  if (l < 10) {
    float a = fc2b[l];
#pragma unroll
    for (int i = 0; i < 64; ++i) a += fc2w[l * 64 + i] * z1[w * 64 + i];
    yL[w * 10 + l] = a;
  }
  __syncthreads();
  if (l < 10) {
    float m = -1e30f;
#pragma unroll
    for (int i = 0; i < 10; ++i) m = fmaxf(m, yL[w * 10 + i]);
    float s = 0.f;
#pragma unroll
    for (int i = 0; i < 10; ++i) s += expf(yL[w * 10 + i] - m);
    out[n * 10 + l] = yL[w * 10 + l] - m - logf(s);
  }
}

// ---------------------------------------------------------------------------
extern "C" void kernel_launch(void* const* d_in, const int* in_sizes, int n_in,
                              void* d_out, int out_size, void* d_ws, size_t ws_size,
                              hipStream_t stream)
{
  (void)in_sizes; (void)n_in; (void)out_size;
  const float* x    = (const float*)d_in[0];
  const float* w1   = (const float*)d_in[1];
  const float* cb1  = (const float*)d_in[2];
  const float* bn1s = (const float*)d_in[3];
  const float* bn1b = (const float*)d_in[4];
  const float* w2   = (const float*)d_in[5];
  const float* cb2  = (const float*)d_in[6];
  const float* bn2s = (const float*)d_in[7];
  const float* bn2b = (const float*)d_in[8];
  const float* w3   = (const float*)d_in[9];
  const float* cb3  = (const float*)d_in[10];
  const float* bn3s = (const float*)d_in[11];
  const float* bn3b = (const float*)d_in[12];
  const float* cbk  = (const float*)d_in[13];
  const float* fc1w = (const float*)d_in[14];
  const float* fc1b = (const float*)d_in[15];
  const float* fc2w = (const float*)d_in[16];
  const float* fc2b = (const float*)d_in[17];
  float* out = (float*)d_out;

  double* dstats = (double*)d_ws;
  float* fws = (float*)((char*)d_ws + 32768);
  float* a1 = fws;        float* b1 = fws + 64;
  float* a2 = fws + 128;  float* b2 = fws + 160;
  float* a3 = fws + 192;  float* b3 = fws + 224;

  float* recon_out = out;              // [2048,32,4,4]
  float* h_out     = out + 1048576;    // [2048,32,4,4]
  float* loss_out  = out + 2097152;    // scalar
  float* y_out     = out + 2097153;    // [2048,10]

  // fast path needs: 32768 B + (256 + 18432[w2t] + 2359296[y2] + 1048576[t3]
  //                              + 31457280[y1]) * 4 B  = 139,568,128 B
  const bool fast = ws_size >= 139568128ull;

  hipMemsetAsync(d_ws, 0, 32768, stream);

  if (fast) {
    float* w2t = fws + 256;
    float* y2  = fws + 256 + 18432;
    float* t3  = y2 + 2359296;
    float* y1  = t3 + 1048576;

    k0_w2t<<<72, 256, 0, stream>>>(w2, w2t);
    k1_conv1<<<2048, 256, 0, stream>>>(x, w1, cb1, dstats, y1);
    k_finalize<<<1, 64, 0, stream>>>(dstats, bn1s, bn1b, a1, b1, 64, 1.0 / CNT1);
    k3_conv2_fast<<<512, 384, 0, stream>>>(y1, a1, b1, w2t, cb2, y2, dstats + 1024);
    k_finalize<<<1, 64, 0, stream>>>(dstats + 1024, bn2s, bn2b, a2, b2, 32, 1.0 / CNT2);
    k5_conv3<<<256, 256, 0, stream>>>(y2, a2, b2, w3, cb3, t3, dstats + 1536);
    k_finalize<<<1, 64, 0, stream>>>(dstats + 1536, bn3s, bn3b, a3, b3, 32, 1.0 / CNT3);
    k8_vq<<<128, 256, 0, stream>>>(t3, a3, b3, cbk, recon_out, h_out, dstats + 2048);
    k10_fc<<<512, 256, 0, stream>>>(recon_out, h_out, fc1w, fc1b, fc2w, fc2b,
                                    y_out, dstats + 2048, loss_out);
  } else {
    float* y2 = fws + 256;
    float* t3 = fws + 256 + 2359296;

    k1_conv1_stats<<<2048, 256, 0, stream>>>(x, w1, cb1, dstats);
    k_finalize<<<1, 64, 0, stream>>>(dstats, bn1s, bn1b, a1, b1, 64, 1.0 / CNT1);
    k3_conv2<<<2048, 256, 0, stream>>>(x, w1, cb1, a1, b1, w2, cb2, y2, dstats + 1024);
    k_finalize<<<1, 64, 0, stream>>>(dstats + 1024, bn2s, bn2b, a2, b2, 32, 1.0 / CNT2);
    k5_conv3<<<256, 256, 0, stream>>>(y2, a2, b2, w3, cb3, t3, dstats + 1536);
    k_finalize<<<1, 64, 0, stream>>>(dstats + 1536, bn3s, bn3b, a3, b3, 32, 1.0 / CNT3);
    k8_vq<<<128, 256, 0, stream>>>(t3, a3, b3, cbk, recon_out, h_out, dstats + 2048);
    k10_fc<<<512, 256, 0, stream>>>(recon_out, h_out, fc1w, fc1b, fc2w, fc2b,
                                    y_out, dstats + 2048, loss_out);
  }
}

// Round 6
// 462.416 us; speedup vs baseline: 1.2694x; 1.2694x over previous
//
#include <hip/hip_runtime.h>
#include <math.h>

// ---------------------------------------------------------------------------
// VQ-VAE-ish CIFAR pipeline, fp32 throughout (argmin flip-sensitivity forbids
// bf16 anywhere before the VQ stage).
//
// R5 -> R6: revert the __launch_bounds__ min-waves hint on k1/k5. R5 showed
// the hint moved the register allocator to the 64-VGPR bucket (VGPR=64) and
// spilled ~870 B/thread to scratch (WRITE_SIZE 583 MB vs 126 MB of real y1
// writes) -> k1 became a 260 µs memory-bound kernel. k3 keeps (384,3),
// which worked (k3 left the top-5); k5 keeps the bank-striped w3c layout.
// ---------------------------------------------------------------------------

#define CNT1 460800.0   /* 2048*15*15 */
#define CNT2 73728.0    /* 2048*6*6   */
#define CNT3 32768.0    /* 2048*4*4   */

// ---------------- K0: pack w2 -> [cc8][r=ci*9+s][cog][half] ----------------
// half 0 -> co=cog, half 1 -> co=cog+16, so a float2 read gives both.
__global__ void k0_w2t(const float* __restrict__ w2, float* __restrict__ w2t)
{
  const int idx = blockIdx.x * 256 + threadIdx.x;   // 18432 total
  const int half = idx & 1, cog = (idx >> 1) & 15;
  const int r = (idx >> 5) % 72, cc = idx / 2304;
  const int o = cog + 16 * half;
  w2t[idx] = w2[o * 576 + cc * 72 + r];
}

// ---------------- k1 segment helper ----------------
// CB: base input col (mult of 4), W4: float4s per row, J0/CNT: pooled cols.
template<int CB, int W4, int J0, int CNT>
__device__ __forceinline__ void conv1_seg(const float* img, const float* wr,
                                          int prow, float bias, float* vout)
{
  float acc[CNT][4];
#pragma unroll
  for (int j = 0; j < CNT; ++j) { acc[j][0] = 0; acc[j][1] = 0; acc[j][2] = 0; acc[j][3] = 0; }
#pragma unroll
  for (int cin = 0; cin < 3; ++cin) {
    float pt[4][4 * W4];
    const float4* src = (const float4*)&img[cin * 1024 + (2 * prow) * 32 + CB];
#pragma unroll
    for (int r = 0; r < 4; ++r)
#pragma unroll
      for (int u = 0; u < W4; ++u) {
        float4 f = src[r * 8 + u];
        pt[r][u * 4 + 0] = f.x; pt[r][u * 4 + 1] = f.y;
        pt[r][u * 4 + 2] = f.z; pt[r][u * 4 + 3] = f.w;
      }
#pragma unroll
    for (int jj = 0; jj < CNT; ++jj) {
      const int c0 = 2 * (J0 + jj) - CB;
#pragma unroll
      for (int kh = 0; kh < 3; ++kh)
#pragma unroll
        for (int kw = 0; kw < 3; ++kw) {
          const float w_ = wr[cin * 9 + kh * 3 + kw];
          acc[jj][0] += pt[kh][c0 + kw] * w_;
          acc[jj][1] += pt[kh][c0 + 1 + kw] * w_;
          acc[jj][2] += pt[kh + 1][c0 + kw] * w_;
          acc[jj][3] += pt[kh + 1][c0 + 1 + kw] * w_;
        }
    }
  }
#pragma unroll
  for (int jj = 0; jj < CNT; ++jj) {
    float v = fmaxf(fmaxf(acc[jj][0], acc[jj][1]), fmaxf(acc[jj][2], acc[jj][3])) + bias;
    vout[J0 + jj] = fmaxf(v, 0.f);
  }
}

// ---------------- K1 fast: conv1+pool+relu -> y1 + stats ----------------
// thread = (ch 0..63, rslot 0..3); each wave = one rslot -> all LDS reads
// are full-wave broadcasts. Plain launch bounds: R5's (256,4) hint pushed
// the RA into the 64-VGPR bucket and spilled ~870 B/thread to scratch.
__global__ __launch_bounds__(256) void k1_conv1(
    const float* __restrict__ x, const float* __restrict__ w1,
    const float* __restrict__ b1, double* __restrict__ dstats,
    float* __restrict__ y1)
{
  __shared__ float img[3072];
  __shared__ float red_s[256], red_q[256];
  const int n = blockIdx.x, t = threadIdx.x;
  const float4* xin = (const float4*)(x + n * 3072);
  float4* img4 = (float4*)img;
  for (int i = t; i < 768; i += 256) img4[i] = xin[i];
  const int ch = t & 63, rslot = t >> 6;
  float wr[27];
#pragma unroll
  for (int k = 0; k < 27; ++k) wr[k] = w1[ch * 27 + k];
  const float bias = b1[ch];
  __syncthreads();
  float s = 0.f, ss = 0.f;
  for (int prow = rslot; prow < 15; prow += 4) {
    float vout[15];
    conv1_seg<0, 4, 0, 7>(img, wr, prow, bias, vout);
    conv1_seg<12, 4, 7, 5>(img, wr, prow, bias, vout);
    conv1_seg<24, 2, 12, 3>(img, wr, prow, bias, vout);
    float4* dst = (float4*)(y1 + n * 15360 + ch * 240 + prow * 16);
    dst[0] = make_float4(vout[0], vout[1], vout[2], vout[3]);
    dst[1] = make_float4(vout[4], vout[5], vout[6], vout[7]);
    dst[2] = make_float4(vout[8], vout[9], vout[10], vout[11]);
    dst[3] = make_float4(vout[12], vout[13], vout[14], 0.f);
#pragma unroll
    for (int j = 0; j < 15; ++j) { s += vout[j]; ss += vout[j] * vout[j]; }
  }
  red_s[t] = s; red_q[t] = ss;
  __syncthreads();
  if (t < 64) {
    float rs = red_s[t] + red_s[t + 64] + red_s[t + 128] + red_s[t + 192];
    float rq = red_q[t] + red_q[t + 64] + red_q[t + 128] + red_q[t + 192];
    atomicAdd(&dstats[t * 16], (double)rs);
    atomicAdd(&dstats[t * 16 + 8], (double)rq);
  }
}

// ---------------- K1 fallback (stats only) ----------------
__global__ __launch_bounds__(256) void k1_conv1_stats(
    const float* __restrict__ x, const float* __restrict__ w1,
    const float* __restrict__ b1, double* __restrict__ dstats)
{
  __shared__ float img[3072];
  __shared__ float red[512];
  const int n = blockIdx.x, t = threadIdx.x;
  const float4* xin = (const float4*)(x + n * 3072);
  float4* img4 = (float4*)img;
  for (int i = t; i < 768; i += 256) img4[i] = xin[i];
  const int c = t >> 2, q = t & 3;
  float wr[27];
#pragma unroll
  for (int k = 0; k < 27; ++k) wr[k] = w1[c * 27 + k];
  const float bias = b1[c];
  __syncthreads();
  float s = 0.f, ss = 0.f;
  for (int p = q; p < 225; p += 4) {
    const int i = p / 15, j = p % 15;
    float a0 = 0, a1 = 0, a2 = 0, a3 = 0;
#pragma unroll
    for (int cin = 0; cin < 3; ++cin) {
      float pt[4][4];
#pragma unroll
      for (int r = 0; r < 4; ++r) {
        const float2* row = (const float2*)&img[cin * 1024 + (2 * i + r) * 32 + 2 * j];
        float2 u = row[0], v = row[1];
        pt[r][0] = u.x; pt[r][1] = u.y; pt[r][2] = v.x; pt[r][3] = v.y;
      }
#pragma unroll
      for (int kh = 0; kh < 3; ++kh)
#pragma unroll
        for (int kw = 0; kw < 3; ++kw) {
          const float wv = wr[cin * 9 + kh * 3 + kw];
          a0 += pt[kh][kw] * wv;     a1 += pt[kh][kw + 1] * wv;
          a2 += pt[kh + 1][kw] * wv; a3 += pt[kh + 1][kw + 1] * wv;
        }
    }
    float v = fmaxf(fmaxf(a0, a1), fmaxf(a2, a3)) + bias;
    v = fmaxf(v, 0.f);
    s += v; ss += v * v;
  }
  red[t * 2] = s; red[t * 2 + 1] = ss;
  __syncthreads();
  if (q == 0) {
    float rs = red[t * 2] + red[(t + 1) * 2] + red[(t + 2) * 2] + red[(t + 3) * 2];
    float rq = red[t * 2 + 1] + red[(t + 1) * 2 + 1] + red[(t + 2) * 2 + 1] + red[(t + 3) * 2 + 1];
    atomicAdd(&dstats[c * 16], (double)rs);
    atomicAdd(&dstats[c * 16 + 8], (double)rq);
  }
}

// ---------------- KF: finalize BN -> affine ----------------
__global__ void k_finalize(const double* __restrict__ dstats,
                           const float* __restrict__ scale, const float* __restrict__ bias,
                           float* __restrict__ a, float* __restrict__ b, int C, double inv_cnt)
{
  int c = threadIdx.x;
  if (c < C) {
    double mean = dstats[c * 16] * inv_cnt;
    double var = dstats[c * 16 + 8] * inv_cnt - mean * mean;
    double ai = (double)scale[c] / sqrt(var + 1e-5);
    a[c] = (float)ai;
    b[c] = (float)((double)bias[c] - mean * ai);
  }
}

// ---------------- K3 fast: BN1(y1) -> conv2 + pool + relu + stats ----------
// 384 threads, 4 images/block, 8-channel chunks. thread = (irow, img, cog),
// owns co={cog,cog+16} x full pooled row. (384,3) verified good in R5
// (k3 left the top-5 after this change).
__global__ __launch_bounds__(384, 3) void k3_conv2_fast(
    const float* __restrict__ y1, const float* __restrict__ a1f,
    const float* __restrict__ b1f, const float* __restrict__ w2t,
    const float* __restrict__ b2, float* __restrict__ y2,
    double* __restrict__ dstats2)
{
  __shared__ float y1n[4 * 1928];     // 4 imgs x (8ch x 240 + 8 pad)
  __shared__ float w2c[72 * 32];      // [r=ci*9+s][cog][half]
  __shared__ float sum2L[32], ss2L[32];
  const int t = threadIdx.x;
  const int n0 = blockIdx.x * 4;
  if (t < 32) { sum2L[t] = 0.f; ss2L[t] = 0.f; }
  const int irow = t / 64;            // 0..5, one per wave
  const int img = (t >> 4) & 3;
  const int cog = t & 15;

  float acc[2][6][4];
#pragma unroll
  for (int h = 0; h < 2; ++h)
#pragma unroll
    for (int j = 0; j < 6; ++j) { acc[h][j][0] = 0; acc[h][j][1] = 0; acc[h][j][2] = 0; acc[h][j][3] = 0; }

  for (int cc = 0; cc < 8; ++cc) {
    __syncthreads();
    // stage y1 chunk with BN1 affine (4 x 480 float4, coalesced)
    for (int idx = t; idx < 1920; idx += 384) {
      const int im = idx / 480, wi = idx - im * 480;
      const int ch = cc * 8 + wi / 60;
      const float an = a1f[ch], bn = b1f[ch];
      float4 v = ((const float4*)(y1 + (n0 + im) * 15360 + cc * 1920))[wi];
      v.x = an * v.x + bn; v.y = an * v.y + bn;
      v.z = an * v.z + bn; v.w = an * v.w + bn;
      ((float4*)y1n)[im * 482 + wi] = v;
    }
    // stage w2 chunk (576 float4, contiguous)
    for (int idx = t; idx < 576; idx += 384)
      ((float4*)w2c)[idx] = ((const float4*)(w2t + cc * 2304))[idx];
    __syncthreads();
    for (int ci = 0; ci < 8; ++ci) {
      float wv0[9], wv1[9];
#pragma unroll
      for (int s = 0; s < 9; ++s) {
        float2 wp = *(const float2*)&w2c[(ci * 9 + s) * 32 + cog * 2];
        wv0[s] = wp.x; wv1[s] = wp.y;
      }
      float pt[4][16];
      const float4* src = (const float4*)&y1n[img * 1928 + ci * 240 + 2 * irow * 16];
#pragma unroll
      for (int r = 0; r < 4; ++r)
#pragma unroll
        for (int u = 0; u < 4; ++u) {
          float4 f = src[r * 4 + u];
          pt[r][u * 4 + 0] = f.x; pt[r][u * 4 + 1] = f.y;
          pt[r][u * 4 + 2] = f.z; pt[r][u * 4 + 3] = f.w;
        }
#pragma unroll
      for (int j = 0; j < 6; ++j)
#pragma unroll
        for (int kh = 0; kh < 3; ++kh)
#pragma unroll
          for (int kw = 0; kw < 3; ++kw) {
            const float p00 = pt[kh][2 * j + kw],     p01 = pt[kh][2 * j + 1 + kw];
            const float p10 = pt[kh + 1][2 * j + kw], p11 = pt[kh + 1][2 * j + 1 + kw];
            const float w0 = wv0[kh * 3 + kw], w1_ = wv1[kh * 3 + kw];
            acc[0][j][0] += p00 * w0;  acc[0][j][1] += p01 * w0;
            acc[0][j][2] += p10 * w0;  acc[0][j][3] += p11 * w0;
            acc[1][j][0] += p00 * w1_; acc[1][j][1] += p01 * w1_;
            acc[1][j][2] += p10 * w1_; acc[1][j][3] += p11 * w1_;
          }
    }
  }
  // epilogue: pool+bias+relu, store y2, stats
  const int n = n0 + img;
#pragma unroll
  for (int half = 0; half < 2; ++half) {
    const int co = cog + half * 16;
    const float bias = b2[co];
    float s = 0.f, sq = 0.f;
#pragma unroll
    for (int j = 0; j < 6; ++j) {
      float v = fmaxf(fmaxf(acc[half][j][0], acc[half][j][1]),
                      fmaxf(acc[half][j][2], acc[half][j][3])) + bias;
      v = fmaxf(v, 0.f);
      y2[n * 1152 + co * 36 + irow * 6 + j] = v;
      s += v; sq += v * v;
    }
    atomicAdd(&sum2L[co], s);
    atomicAdd(&ss2L[co], sq);
  }
  __syncthreads();
  if (t < 32) {
    atomicAdd(&dstats2[t * 16], (double)sum2L[t]);
    atomicAdd(&dstats2[t * 16 + 8], (double)ss2L[t]);
  }
}

// ---------------- K3 fallback (R2 version): recompute conv1 in-block -------
__global__ __launch_bounds__(256) void k3_conv2(
    const float* __restrict__ x, const float* __restrict__ w1,
    const float* __restrict__ b1, const float* __restrict__ a1f,
    const float* __restrict__ b1f, const float* __restrict__ w2,
    const float* __restrict__ b2, float* __restrict__ y2,
    double* __restrict__ dstats2)
{
  __shared__ float img[3072];
  __shared__ float y1n[16 * 240];
  __shared__ float w2c[144 * 32];
  __shared__ float sum2L[32], ss2L[32];
  const int n = blockIdx.x, t = threadIdx.x;
  if (t < 32) { sum2L[t] = 0.f; ss2L[t] = 0.f; }
  const float4* xin = (const float4*)(x + n * 3072);
  float4* img4 = (float4*)img;
  for (int i = t; i < 768; i += 256) img4[i] = xin[i];

  const int co = t & 31, irow = t >> 5;
  const bool activeC = (irow < 6);

  float acc[6][4];
#pragma unroll
  for (int j = 0; j < 6; ++j) { acc[j][0] = 0; acc[j][1] = 0; acc[j][2] = 0; acc[j][3] = 0; }

  const int cA = t >> 4, qA = t & 15;

  for (int cc = 0; cc < 4; ++cc) {
    __syncthreads();
    {
      const int ch = cc * 16 + cA;
      float wr[27];
#pragma unroll
      for (int k = 0; k < 27; ++k) wr[k] = w1[ch * 27 + k];
      const float bias = b1[ch];
      const float an = a1f[ch], bn = b1f[ch];
      for (int p = qA; p < 225; p += 16) {
        const int i = p / 15, j = p % 15;
        float a0 = 0, a1 = 0, a2 = 0, a3 = 0;
#pragma unroll
        for (int cin = 0; cin < 3; ++cin) {
          float pt[4][4];
#pragma unroll
          for (int r = 0; r < 4; ++r) {
            const float2* row = (const float2*)&img[cin * 1024 + (2 * i + r) * 32 + 2 * j];
            float2 u = row[0], v = row[1];
            pt[r][0] = u.x; pt[r][1] = u.y; pt[r][2] = v.x; pt[r][3] = v.y;
          }
#pragma unroll
          for (int kh = 0; kh < 3; ++kh)
#pragma unroll
            for (int kw = 0; kw < 3; ++kw) {
              const float wv = wr[cin * 9 + kh * 3 + kw];
              a0 += pt[kh][kw] * wv;     a1 += pt[kh][kw + 1] * wv;
              a2 += pt[kh + 1][kw] * wv; a3 += pt[kh + 1][kw + 1] * wv;
            }
        }
        float v = fmaxf(fmaxf(a0, a1), fmaxf(a2, a3)) + bias;
        v = fmaxf(v, 0.f);
        y1n[cA * 240 + i * 16 + j] = an * v + bn;
      }
    }
    for (int idx = t; idx < 4608; idx += 256) {
      const int o = idx & 31, r = idx >> 5;
      w2c[r * 32 + o] = w2[o * 576 + cc * 144 + r];
    }
    __syncthreads();
    if (activeC) {
      for (int ci = 0; ci < 16; ++ci) {
        float wv[9];
#pragma unroll
        for (int s = 0; s < 9; ++s) wv[s] = w2c[(ci * 9 + s) * 32 + co];
        float pt[4][16];
        const float4* src = (const float4*)&y1n[ci * 240 + (2 * irow) * 16];
#pragma unroll
        for (int r = 0; r < 4; ++r)
#pragma unroll
          for (int u = 0; u < 4; ++u) {
            float4 f = src[r * 4 + u];
            pt[r][u * 4] = f.x; pt[r][u * 4 + 1] = f.y;
            pt[r][u * 4 + 2] = f.z; pt[r][u * 4 + 3] = f.w;
          }
#pragma unroll
        for (int j = 0; j < 6; ++j) {
#pragma unroll
          for (int kh = 0; kh < 3; ++kh)
#pragma unroll
            for (int kw = 0; kw < 3; ++kw) {
              const float w_ = wv[kh * 3 + kw];
              acc[j][0] += pt[kh][2 * j + kw] * w_;
              acc[j][1] += pt[kh][2 * j + 1 + kw] * w_;
              acc[j][2] += pt[kh + 1][2 * j + kw] * w_;
              acc[j][3] += pt[kh + 1][2 * j + 1 + kw] * w_;
            }
        }
      }
    }
  }
  if (activeC) {
    const float bias = b2[co];
    float s = 0.f, sq = 0.f;
#pragma unroll
    for (int j = 0; j < 6; ++j) {
      float v = fmaxf(fmaxf(acc[j][0], acc[j][1]), fmaxf(acc[j][2], acc[j][3])) + bias;
      v = fmaxf(v, 0.f);
      y2[n * 1152 + co * 36 + irow * 6 + j] = v;
      s += v; sq += v * v;
    }
    atomicAdd(&sum2L[co], s);
    atomicAdd(&ss2L[co], sq);
  }
  __syncthreads();
  if (t < 32) {
    atomicAdd(&dstats2[t * 16], (double)sum2L[t]);
    atomicAdd(&dstats2[t * 16 + 8], (double)ss2L[t]);
  }
}

// ---------------- K5: BN2 -> conv3 + bias + relu + stats ----------------
// w3c bank-striped [r][c] (kept from R5); plain launch bounds (R5's (256,4)
// risked the same spill pathology as k1).
__global__ __launch_bounds__(256) void k5_conv3(
    const float* __restrict__ y2, const float* __restrict__ a2f,
    const float* __restrict__ b2f, const float* __restrict__ w3,
    const float* __restrict__ b3, float* __restrict__ t3,
    double* __restrict__ dstats3)
{
  __shared__ float y2n[8 * 1152];
  __shared__ float w3c[144 * 32];   // [r][c]
  __shared__ float sum3L[32], ss3L[32];
  const int blk = blockIdx.x, t = threadIdx.x;
  if (t < 32) { sum3L[t] = 0.f; ss3L[t] = 0.f; }
  for (int idx = t; idx < 9216; idx += 256) {
    const int ci = (idx % 1152) / 36;
    y2n[idx] = a2f[ci] * y2[blk * 9216 + idx] + b2f[ci];
  }
  const int il = t >> 5, c = t & 31;
  float acc[16];
#pragma unroll
  for (int p = 0; p < 16; ++p) acc[p] = 0.f;
  for (int ch = 0; ch < 2; ++ch) {
    __syncthreads();
    for (int idx = t; idx < 4608; idx += 256) {
      const int o = idx & 31, r = idx >> 5;
      w3c[r * 32 + o] = w3[o * 288 + ch * 144 + r];
    }
    __syncthreads();
    for (int ci = 0; ci < 16; ++ci) {
      float wv[9];
#pragma unroll
      for (int s = 0; s < 9; ++s) wv[s] = w3c[(ci * 9 + s) * 32 + c];
      float pt[36];
      const float4* src = (const float4*)&y2n[il * 1152 + (ch * 16 + ci) * 36];
#pragma unroll
      for (int u = 0; u < 9; ++u) {
        float4 f = src[u];
        pt[u * 4] = f.x; pt[u * 4 + 1] = f.y; pt[u * 4 + 2] = f.z; pt[u * 4 + 3] = f.w;
      }
#pragma unroll
      for (int i = 0; i < 4; ++i)
#pragma unroll
        for (int j = 0; j < 4; ++j) {
          float a_ = 0.f;
#pragma unroll
          for (int kh = 0; kh < 3; ++kh)
#pragma unroll
            for (int kw = 0; kw < 3; ++kw)
              a_ += pt[(i + kh) * 6 + j + kw] * wv[kh * 3 + kw];
          acc[i * 4 + j] += a_;
        }
    }
  }
  const float bias = b3[c];
  float s = 0.f, sq = 0.f;
  float vout[16];
#pragma unroll
  for (int p = 0; p < 16; ++p) {
    float v = fmaxf(acc[p] + bias, 0.f);
    vout[p] = v; s += v; sq += v * v;
  }
  const int n = blk * 8 + il;
  float4* dst = (float4*)&t3[(n * 32 + c) * 16];
#pragma unroll
  for (int u = 0; u < 4; ++u)
    dst[u] = make_float4(vout[u * 4], vout[u * 4 + 1], vout[u * 4 + 2], vout[u * 4 + 3]);
  atomicAdd(&sum3L[c], s);
  atomicAdd(&ss3L[c], sq);
  __syncthreads();
  if (t < 32) {
    atomicAdd(&dstats3[t * 16], (double)sum3L[t]);
    atomicAdd(&dstats3[t * 16 + 8], (double)ss3L[t]);
  }
}

// ---------------- K8: BN3 affine + VQ ----------------
__global__ __launch_bounds__(256) void k8_vq(
    const float* __restrict__ t3, const float* __restrict__ a3f,
    const float* __restrict__ b3f, const float* __restrict__ cbg,
    float* __restrict__ recon, float* __restrict__ hout,
    double* __restrict__ dloss)
{
  __shared__ float cb[3200];
  __shared__ float n2[100];
  const int t = threadIdx.x;
  for (int i = t; i < 3200; i += 256) cb[i] = cbg[i];
  __syncthreads();
  if (t < 100) {
    float s = 0.f;
#pragma unroll
    for (int c = 0; c < 32; ++c) { float v = cb[t * 32 + c]; s += v * v; }
    n2[t] = s;
  }
  __syncthreads();
  const int v = blockIdx.x * 256 + t;
  const int b = v >> 4, p = v & 15;
  float z[32];
  float z2 = 0.f;
#pragma unroll
  for (int c = 0; c < 32; ++c) {
    const float zz = a3f[c] * t3[b * 512 + c * 16 + p] + b3f[c];
    hout[b * 512 + c * 16 + p] = zz;
    z[c] = zz; z2 += zz * zz;
  }
  float best = 1e30f; int bi = 0;
  for (int k = 0; k < 100; ++k) {
    float dot = 0.f;
#pragma unroll
    for (int c = 0; c < 32; ++c) dot += z[c] * cb[k * 32 + c];
    const float d = z2 + n2[k] - 2.f * dot;
    if (d < best) { best = d; bi = k; }
  }
  float lsum = 0.f;
#pragma unroll
  for (int c = 0; c < 32; ++c) {
    const float qv = cb[bi * 32 + c];
    recon[b * 512 + c * 16 + p] = qv;
    const float df = qv - z[c];
    lsum += df * df;
  }
#pragma unroll
  for (int off = 32; off > 0; off >>= 1) lsum += __shfl_down(lsum, off, 64);
  if ((t & 63) == 0) atomicAdd(dloss, (double)lsum);
}

// ---------------- K10: fc1+relu+fc2+log_softmax (+ vq_loss finalize) -------
__global__ __launch_bounds__(256) void k10_fc(
    const float* __restrict__ recon, const float* __restrict__ h,
    const float* __restrict__ fc1w, const float* __restrict__ fc1b,
    const float* __restrict__ fc2w, const float* __restrict__ fc2b,
    float* __restrict__ out, const double* __restrict__ dloss,
    float* __restrict__ loss_out)
{
  __shared__ float flat[4 * 512];
  __shared__ float z1[4 * 64];
  __shared__ float yL[4 * 10];
  const int t = threadIdx.x;
  const int w = t >> 6, l = t & 63;
  const int n = blockIdx.x * 4 + w;
  if (blockIdx.x == 0 && t == 0)
    loss_out[0] = (float)(1.25 * dloss[0] / (32768.0 * 32.0));
  for (int k = l; k < 512; k += 64)
    flat[w * 512 + k] = 0.5f * recon[n * 512 + k] + h[n * 512 + k];
  __syncthreads();
  float acc = fc1b[l];
  const float4* wrow = (const float4*)(fc1w + l * 512);
  const float4* frow = (const float4*)(flat + w * 512);
  for (int k4 = 0; k4 < 128; ++k4) {
    const float4 wv = wrow[k4], fv = frow[k4];
    acc += wv.x * fv.x + wv.y * fv.y + wv.z * fv.z + wv.w * fv.w;
  }
  z1[w * 64 + l] = fmaxf(acc, 0.f);
  __syncthreads();
  if (l < 10) {
    float a = fc2b[l];
#pragma unroll
    for (int i = 0; i < 64; ++i) a += fc2w[l * 64 + i] * z1[w * 64 + i];
    yL[w * 10 + l] = a;
  }
  __syncthreads();
  if (l < 10) {
    float m = -1e30f;
#pragma unroll
    for (int i = 0; i < 10; ++i) m = fmaxf(m, yL[w * 10 + i]);
    float s = 0.f;
#pragma unroll
    for (int i = 0; i < 10; ++i) s += expf(yL[w * 10 + i] - m);
    out[n * 10 + l] = yL[w * 10 + l] - m - logf(s);
  }
}

// ---------------------------------------------------------------------------
extern "C" void kernel_launch(void* const* d_in, const int* in_sizes, int n_in,
                              void* d_out, int out_size, void* d_ws, size_t ws_size,
                              hipStream_t stream)
{
  (void)in_sizes; (void)n_in; (void)out_size;
  const float* x    = (const float*)d_in[0];
  const float* w1   = (const float*)d_in[1];
  const float* cb1  = (const float*)d_in[2];
  const float* bn1s = (const float*)d_in[3];
  const float* bn1b = (const float*)d_in[4];
  const float* w2   = (const float*)d_in[5];
  const float* cb2  = (const float*)d_in[6];
  const float* bn2s = (const float*)d_in[7];
  const float* bn2b = (const float*)d_in[8];
  const float* w3   = (const float*)d_in[9];
  const float* cb3  = (const float*)d_in[10];
  const float* bn3s = (const float*)d_in[11];
  const float* bn3b = (const float*)d_in[12];
  const float* cbk  = (const float*)d_in[13];
  const float* fc1w = (const float*)d_in[14];
  const float* fc1b = (const float*)d_in[15];
  const float* fc2w = (const float*)d_in[16];
  const float* fc2b = (const float*)d_in[17];
  float* out = (float*)d_out;

  double* dstats = (double*)d_ws;
  float* fws = (float*)((char*)d_ws + 32768);
  float* a1 = fws;        float* b1 = fws + 64;
  float* a2 = fws + 128;  float* b2 = fws + 160;
  float* a3 = fws + 192;  float* b3 = fws + 224;

  float* recon_out = out;              // [2048,32,4,4]
  float* h_out     = out + 1048576;    // [2048,32,4,4]
  float* loss_out  = out + 2097152;    // scalar
  float* y_out     = out + 2097153;    // [2048,10]

  // fast path needs: 32768 B + (256 + 18432[w2t] + 2359296[y2] + 1048576[t3]
  //                              + 31457280[y1]) * 4 B  = 139,568,128 B
  const bool fast = ws_size >= 139568128ull;

  hipMemsetAsync(d_ws, 0, 32768, stream);

  if (fast) {
    float* w2t = fws + 256;
    float* y2  = fws + 256 + 18432;
    float* t3  = y2 + 2359296;
    float* y1  = t3 + 1048576;

    k0_w2t<<<72, 256, 0, stream>>>(w2, w2t);
    k1_conv1<<<2048, 256, 0, stream>>>(x, w1, cb1, dstats, y1);
    k_finalize<<<1, 64, 0, stream>>>(dstats, bn1s, bn1b, a1, b1, 64, 1.0 / CNT1);
    k3_conv2_fast<<<512, 384, 0, stream>>>(y1, a1, b1, w2t, cb2, y2, dstats + 1024);
    k_finalize<<<1, 64, 0, stream>>>(dstats + 1024, bn2s, bn2b, a2, b2, 32, 1.0 / CNT2);
    k5_conv3<<<256, 256, 0, stream>>>(y2, a2, b2, w3, cb3, t3, dstats + 1536);
    k_finalize<<<1, 64, 0, stream>>>(dstats + 1536, bn3s, bn3b, a3, b3, 32, 1.0 / CNT3);
    k8_vq<<<128, 256, 0, stream>>>(t3, a3, b3, cbk, recon_out, h_out, dstats + 2048);
    k10_fc<<<512, 256, 0, stream>>>(recon_out, h_out, fc1w, fc1b, fc2w, fc2b,
                                    y_out, dstats + 2048, loss_out);
  } else {
    float* y2 = fws + 256;
    float* t3 = fws + 256 + 2359296;

    k1_conv1_stats<<<2048, 256, 0, stream>>>(x, w1, cb1, dstats);
    k_finalize<<<1, 64, 0, stream>>>(dstats, bn1s, bn1b, a1, b1, 64, 1.0 / CNT1);
    k3_conv2<<<2048, 256, 0, stream>>>(x, w1, cb1, a1, b1, w2, cb2, y2, dstats + 1024);
    k_finalize<<<1, 64, 0, stream>>>(dstats + 1024, bn2s, bn2b, a2, b2, 32, 1.0 / CNT2);
    k5_conv3<<<256, 256, 0, stream>>>(y2, a2, b2, w3, cb3, t3, dstats + 1536);
    k_finalize<<<1, 64, 0, stream>>>(dstats + 1536, bn3s, bn3b, a3, b3, 32, 1.0 / CNT3);
    k8_vq<<<128, 256, 0, stream>>>(t3, a3, b3, cbk, recon_out, h_out, dstats + 2048);
    k10_fc<<<512, 256, 0, stream>>>(recon_out, h_out, fc1w, fc1b, fc2w, fc2b,
                                    y_out, dstats + 2048, loss_out);
  }
}